// Round 1
// baseline (233.051 us; speedup 1.0000x reference)
//
#include <hip/hip_runtime.h>
#include <math.h>

#pragma clang fp contract(off)

#define HH 96
#define WW 96
#define NV 9120          // 95*96 vertical candidates (also 96*95 horizontal)
#define NC 18240         // total candidates per image
#define NPIX 9216
#define NCHUNK 16
#define CHS 1140         // 18240/16
#define BIGF 1000000.0f

// ---------------- K1: central-difference normals + zero pix accumulator ----
__global__ void k_normals(const float* __restrict__ S, float* __restrict__ N,
                          double* pixAcc){
#pragma clang fp contract(off)
  int p = blockIdx.x*256 + threadIdx.x;
  if (p == 0) *pixAcc = 0.0;
  if (p >= NPIX) return;
  int i = p / WW, j = p % WW;
  float gr, gc;
  if (i == 0)            gr = S[WW + j] - S[j];
  else if (i == HH-1)    gr = S[(HH-1)*WW+j] - S[(HH-2)*WW+j];
  else                   gr = (S[(i+1)*WW+j] - S[(i-1)*WW+j]) / 2.0f;
  if (j == 0)            gc = S[i*WW+1] - S[i*WW];
  else if (j == WW-1)    gc = S[i*WW+WW-1] - S[i*WW+WW-2];
  else                   gc = (S[i*WW+j+1] - S[i*WW+j-1]) / 2.0f;
  N[p*2]   = gr;
  N[p*2+1] = gc;
}

// ---------------- K2: zero-crossing extraction for pred and gt -------------
__global__ void k_extract(const float* __restrict__ PRs, const float* __restrict__ GTs,
                          float* prR, float* prC, int* prM,
                          float* gtR, float* gtC, float* gtS){
#pragma clang fp contract(off)
  int t = blockIdx.x*256 + threadIdx.x;
  if (t >= 2*NC) return;
  const float* S = (t < NC) ? PRs : GTs;
  int u = (t < NC) ? t : t - NC;
  float v1, v2, r, c;
  if (u < NV){                      // vertical pair (i0, j)-(i0+1, j)
    int i0 = u / WW, j = u % WW;
    v1 = S[i0*WW+j]; v2 = S[(i0+1)*WW+j];
    float a1 = fabsf(v1), a2 = fabsf(v2);
    float den = (a1 + a2) + 1e-8f;      // left-assoc as reference
    float a = a1 / den;                  // IEEE-correct div
    float i0f = (float)i0;
    r = (v1 == 0.0f) ? i0f : ((v2 == 0.0f) ? (i0f + 1.0f) : (i0f + a));
    c = (float)j;
  } else {                          // horizontal pair (i, j0)-(i, j0+1)
    int u2 = u - NV;
    int i = u2 / (WW-1), j0 = u2 % (WW-1);
    v1 = S[i*WW+j0]; v2 = S[i*WW+j0+1];
    float a1 = fabsf(v1), a2 = fabsf(v2);
    float den = (a1 + a2) + 1e-8f;
    float b = a1 / den;
    float j0f = (float)j0;
    c = (v1 == 0.0f) ? j0f : ((v2 == 0.0f) ? (j0f + 1.0f) : (j0f + b));
    r = (float)i;
  }
  int m = (v1 == 0.0f) || (v2 == 0.0f) || ((v1*v2) < 0.0f);
  if (t < NC){ prR[u] = r; prC[u] = c; prM[u] = m; }
  else {
    float gr = m ? r : BIGF;
    float gc = m ? c : BIGF;
    gtR[u] = gr; gtC[u] = gc;
    gtS[u] = (gr*gr) + (gc*gc);
  }
}

// ---------------- K3a: brute-force NN partial mins (16 gt chunks) ----------
__global__ __launch_bounds__(256) void k_nnpart(
    const float* __restrict__ prR, const float* __restrict__ prC,
    const float* __restrict__ gtR, const float* __restrict__ gtC,
    const float* __restrict__ gtS, float* pmin, int* pidx){
#pragma clang fp contract(off)
  int k  = blockIdx.x*256 + threadIdx.x;
  int ch = blockIdx.y;
  if (k >= NC) return;
  float rp = prR[k], cp = prC[k];
  float sp = (rp*rp) + (cp*cp);          // matches (pr_pts**2).sum(1)
  float best = 3.4e38f;
  int bidx = ch*CHS;
  int e = ch*CHS + CHS;
  for (int jg = ch*CHS; jg < e; ++jg){   // jg uniform -> scalar loads
    float rg = gtR[jg], cg = gtC[jg], sg = gtS[jg];
    float cross = fmaf(cp, cg, rp*rg);   // BLAS sgemm K=2 fma hypothesis
    float d2 = (sp + sg) - (2.0f*cross);
    d2 = fmaxf(d2, 0.0f);
    if (d2 < best){ best = d2; bidx = jg; }   // first-min tie-break
  }
  pmin[k*NCHUNK + ch] = best;
  pidx[k*NCHUNK + ch] = bidx;
}

// ---------------- K3b: combine, normals gather, dot, vals, pix -------------
__global__ __launch_bounds__(256) void k_dot(
    const float* __restrict__ PRs, const float* __restrict__ N,
    const float* __restrict__ prR, const float* __restrict__ prC,
    const int* __restrict__ prM,
    const float* __restrict__ gtR, const float* __restrict__ gtC,
    const float* __restrict__ pmin, const int* __restrict__ pidx,
    float* dotA, double* pixAcc){
#pragma clang fp contract(off)
  int k = blockIdx.x*256 + threadIdx.x;
  double pv = 0.0;
  if (k < NC){
    float best = pmin[k*NCHUNK];
    int   bidx = pidx[k*NCHUNK];
    for (int c2 = 1; c2 < NCHUNK; ++c2){        // ascending chunk order
      float b = pmin[k*NCHUNK + c2];
      if (b < best){ best = b; bidx = pidx[k*NCHUNK + c2]; }
    }
    float rp = prR[k], cp = prC[k];
    int r0 = (int)floorf(rp); if (r0 < 0) r0 = 0; if (r0 > HH-1) r0 = HH-1;
    int c0 = (int)floorf(cp); if (c0 < 0) c0 = 0; if (c0 > WW-1) c0 = WW-1;
    int r1 = r0 + 1; if (r1 > HH-1) r1 = HH-1;
    int c1 = c0 + 1; if (c1 > WW-1) c1 = WW-1;
    float ar = rp - (float)r0, ac = cp - (float)c0;
    float omr = 1.0f - ar, omc = 1.0f - ac;
    float wa = omr*omc, wb = omr*ac, wc = ar*omc, wd = ar*ac;
    // normals bilinear gather, left-to-right adds, no FMA
    float nr = (((N[(r0*WW+c0)*2]*wa) + (N[(r0*WW+c1)*2]*wb))
               + (N[(r1*WW+c0)*2]*wc)) + (N[(r1*WW+c1)*2]*wd);
    float nc = (((N[(r0*WW+c0)*2+1]*wa) + (N[(r0*WW+c1)*2+1]*wb))
               + (N[(r1*WW+c0)*2+1]*wc)) + (N[(r1*WW+c1)*2+1]*wd);
    float nrm = sqrtf((nr*nr) + (nc*nc));       // np.linalg.norm axis=1
    float den = nrm + 1e-8f;
    float nru = nr / den, ncu = nc / den;
    float dr = gtR[bidx] - rp;
    float dc = gtC[bidx] - cp;
    float dotv = (dr*nru) + (dc*ncu);            // * UPDATE_SCALE(=1) exact
    int contrib = prM[k] && (best <= 9.0f);
    dotA[k] = contrib ? dotv : 0.0f;
    float vals = (((PRs[r0*WW+c0]*wa) + (PRs[r0*WW+c1]*wb))
                 + (PRs[r1*WW+c0]*wc)) + (PRs[r1*WW+c1]*wd);
    pv = prM[k] ? (double)vals : 0.0;
  }
  for (int off = 32; off; off >>= 1) pv += __shfl_down(pv, off, 64);
  __shared__ double sb[4];
  int lane = threadIdx.x & 63, wid = threadIdx.x >> 6;
  if (lane == 0) sb[wid] = pv;
  __syncthreads();
  if (threadIdx.x == 0) atomicAdd(pixAcc, (sb[0]+sb[1])+(sb[2]+sb[3]));
}

// ---------------- K4: per-pixel ordered scatter replication ---------------
// Reference order: pass1(wa) all k asc (vert then horiz), pass2(wb), pass3(wc),
// pass4(wd). Vertical: ac=0 -> wb=wd=+0 (no-op). Horizontal: ar=0 -> wc=wd=+0.
__global__ void k_pixel(const float* __restrict__ PRs,
                        const float* __restrict__ prR, const float* __restrict__ prC,
                        const float* __restrict__ dotA, float* tmp){
#pragma clang fp contract(off)
  int p = blockIdx.x*256 + threadIdx.x;
  if (p >= NPIX) return;
  int i = p / WW, j = p % WW;
  float s = 0.0f;
  // pass1 vertical: wa = (1-ar) at (r0, j)
  for (int i0 = i-1; i0 <= i; ++i0){
    if (i0 < 0 || i0 > HH-2) continue;
    int k = i0*WW + j;
    float r = prR[k];
    int r0 = (int)floorf(r);
    if (r0 == i){
      float ar = r - (float)r0;
      float w = 1.0f - ar;
      s = s + (dotA[k] * w);
    }
  }
  // pass1 horizontal: wa = (1-ac) at (i, c0)
  for (int j0 = j-1; j0 <= j; ++j0){
    if (j0 < 0 || j0 > WW-2) continue;
    int k = NV + i*(WW-1) + j0;
    float c = prC[k];
    int c0 = (int)floorf(c);
    if (c0 == j){
      float ac = c - (float)c0;
      float w = 1.0f - ac;
      s = s + (dotA[k] * w);
    }
  }
  // pass2 horizontal: wb = ac at (i, c0+1)
  for (int j0 = j-2; j0 <= j-1; ++j0){
    if (j0 < 0 || j0 > WW-2) continue;
    int k = NV + i*(WW-1) + j0;
    float c = prC[k];
    int c0 = (int)floorf(c);
    if (c0 == j-1){
      float ac = c - (float)c0;
      s = s + (dotA[k] * ac);
    }
  }
  // pass3 vertical: wc = ar at (r0+1, j)
  for (int i0 = i-2; i0 <= i-1; ++i0){
    if (i0 < 0 || i0 > HH-2) continue;
    int k = i0*WW + j;
    float r = prR[k];
    int r0 = (int)floorf(r);
    if (r0 == i-1){
      float ar = r - (float)r0;
      s = s + (dotA[k] * ar);
    }
  }
  tmp[p] = PRs[p] * s;   // (pred * dSDF) elementwise
}

// ---------------- K5: numpy pairwise sum (9216 = 128 leaves x 72) ----------
__global__ void k_final(const float* __restrict__ tmp, const double* __restrict__ pixAcc,
                        float* out){
#pragma clang fp contract(off)
  __shared__ float buf[128];
  int t = threadIdx.x;                 // 0..127
  const float* a = tmp + t*72;
  float r0=a[0],r1=a[1],r2=a[2],r3=a[3],r4=a[4],r5=a[5],r6=a[6],r7=a[7];
  for (int i = 8; i < 72; i += 8){
    r0 += a[i];   r1 += a[i+1]; r2 += a[i+2]; r3 += a[i+3];
    r4 += a[i+4]; r5 += a[i+5]; r6 += a[i+6]; r7 += a[i+7];
  }
  buf[t] = ((r0+r1)+(r2+r3)) + ((r4+r5)+(r6+r7));
  __syncthreads();
  for (int st = 1; st < 128; st <<= 1){
    if ((t & (2*st - 1)) == 0) buf[t] = buf[t] + buf[t+st];  // left + right
    __syncthreads();
  }
  if (t == 0){
    float inj = buf[0];                // W_INJECT * inj, W=1 exact
    float pix = (float)(*pixAcc);      // W_PIXEL * pix
    out[0] = inj + pix;
  }
}

extern "C" void kernel_launch(void* const* d_in, const int* in_sizes, int n_in,
                              void* d_out, int out_size, void* d_ws, size_t ws_size,
                              hipStream_t stream){
  const float* pred = (const float*)d_in[0];
  const float* gt   = (const float*)d_in[1];
  float* out = (float*)d_out;

  // workspace layout: [pixAcc double][floats...]
  double* pixAcc = (double*)d_ws;
  float* f = (float*)((char*)d_ws + 16);
  float* normals = f;            f += NPIX*2;      // 18432
  float* prR = f;                f += NC;
  float* prC = f;                f += NC;
  float* gtR = f;                f += NC;
  float* gtC = f;                f += NC;
  float* gtS = f;                f += NC;
  float* dotA = f;               f += NC;
  float* tmp = f;                f += NPIX;
  float* pmin = f;               f += NC*NCHUNK;   // 291840
  int*   pidx = (int*)f;         f += NC*NCHUNK;
  int*   prM  = (int*)f;         f += NC;

  k_normals<<<dim3((NPIX+255)/256), dim3(256), 0, stream>>>(pred, normals, pixAcc);
  k_extract<<<dim3((2*NC+255)/256), dim3(256), 0, stream>>>(pred, gt,
                prR, prC, prM, gtR, gtC, gtS);
  k_nnpart<<<dim3((NC+255)/256, NCHUNK), dim3(256), 0, stream>>>(prR, prC,
                gtR, gtC, gtS, pmin, pidx);
  k_dot<<<dim3((NC+255)/256), dim3(256), 0, stream>>>(pred, normals,
                prR, prC, prM, gtR, gtC, pmin, pidx, dotA, pixAcc);
  k_pixel<<<dim3((NPIX+255)/256), dim3(256), 0, stream>>>(pred, prR, prC, dotA, tmp);
  k_final<<<dim3(1), dim3(128), 0, stream>>>(tmp, pixAcc, out);
}

// Round 2
// 118.268 us; speedup vs baseline: 1.9705x; 1.9705x over previous
//
#include <hip/hip_runtime.h>
#include <math.h>

#pragma clang fp contract(off)

#define HH 96
#define WW 96
#define NV 9120          // 95*96 vertical candidates (== 96*95 horizontal)
#define NC 18240         // candidates per image
#define NPIX 9216
#define NCELL 9216       // 96x96 spatial hash cells
#define SLOTS 6          // max gt crossings per cell (generic case: <=2)
#define BIGF 1000000.0f

// ---- K1: normals + zero-crossing extraction (pred & gt) + gt grid insert --
__global__ void k_prep(const float* __restrict__ PR, const float* __restrict__ GT,
                       float* __restrict__ N,
                       float* prR, float* prC, int* prM,
                       float* gtR, float* gtC,
                       int* counts, float4* cells, double* pixAcc){
#pragma clang fp contract(off)
  int t = blockIdx.x*256 + threadIdx.x;
  if (t == 0) *pixAcc = 0.0;
  if (t < NPIX){                       // central-difference normals of pred
    int i = t / WW, j = t % WW;
    float gr, gc;
    if (i == 0)         gr = PR[WW+j] - PR[j];
    else if (i == HH-1) gr = PR[(HH-1)*WW+j] - PR[(HH-2)*WW+j];
    else                gr = (PR[(i+1)*WW+j] - PR[(i-1)*WW+j]) / 2.0f;
    if (j == 0)         gc = PR[i*WW+1] - PR[i*WW];
    else if (j == WW-1) gc = PR[i*WW+WW-1] - PR[i*WW+WW-2];
    else                gc = (PR[i*WW+j+1] - PR[i*WW+j-1]) / 2.0f;
    N[t*2] = gr; N[t*2+1] = gc;
  }
  if (t >= 2*NC) return;
  const float* S = (t < NC) ? PR : GT;
  int u = (t < NC) ? t : t - NC;
  float v1, v2, r, c;
  if (u < NV){                         // vertical pair (i0,j)-(i0+1,j)
    int i0 = u / WW, j = u % WW;
    v1 = S[i0*WW+j]; v2 = S[(i0+1)*WW+j];
    float a1 = fabsf(v1), a2 = fabsf(v2);
    float den = (a1 + a2) + 1e-8f;     // left-assoc as reference
    float a = a1 / den;
    float i0f = (float)i0;
    r = (v1 == 0.0f) ? i0f : ((v2 == 0.0f) ? (i0f + 1.0f) : (i0f + a));
    c = (float)j;
  } else {                             // horizontal pair (i,j0)-(i,j0+1)
    int u2 = u - NV;
    int i = u2 / (WW-1), j0 = u2 % (WW-1);
    v1 = S[i*WW+j0]; v2 = S[i*WW+j0+1];
    float a1 = fabsf(v1), a2 = fabsf(v2);
    float den = (a1 + a2) + 1e-8f;
    float b = a1 / den;
    float j0f = (float)j0;
    c = (v1 == 0.0f) ? j0f : ((v2 == 0.0f) ? (j0f + 1.0f) : (j0f + b));
    r = (float)i;
  }
  int m = (v1 == 0.0f) || (v2 == 0.0f) || ((v1*v2) < 0.0f);
  if (t < NC){ prR[u] = r; prC[u] = c; prM[u] = m; }
  else {
    float gr = m ? r : BIGF;
    float gc = m ? c : BIGF;
    gtR[u] = gr; gtC[u] = gc;
    if (m){                            // insert into spatial grid
      int fr = (int)floorf(r); if (fr < 0) fr = 0; if (fr > HH-1) fr = HH-1;
      int fc = (int)floorf(c); if (fc < 0) fc = 0; if (fc > WW-1) fc = WW-1;
      int cell = fr*WW + fc;
      int slot = atomicAdd(&counts[cell], 1);
      if (slot < SLOTS){
        float sg = (r*r) + (c*c);      // matches (gp**2).sum(1)
        cells[cell*SLOTS + slot] = make_float4(r, c, sg, __int_as_float(u));
      }
    }
  }
}

// ---- K2: grid NN (lexicographic (d2,jg) min == numpy first-index argmin) --
//      fused with normals gather, dot, vals, pix partial reduction
__global__ __launch_bounds__(256) void k_nndot(
    const float* __restrict__ PR, const float* __restrict__ N,
    const float* __restrict__ prR, const float* __restrict__ prC,
    const int* __restrict__ prM,
    const float* __restrict__ gtR, const float* __restrict__ gtC,
    const int* __restrict__ counts, const float4* __restrict__ cells,
    float* dotA, double* pixAcc){
#pragma clang fp contract(off)
  int k = blockIdx.x*256 + threadIdx.x;
  double pv = 0.0;
  if (k < NC){
    float rp = prR[k], cp = prC[k];
    float sp = (rp*rp) + (cp*cp);      // matches (pr_pts**2).sum(1)
    int fr = (int)floorf(rp), fc = (int)floorf(cp);
    int rlo = fr-4; if (rlo < 0) rlo = 0;
    int rhi = fr+4; if (rhi > HH-1) rhi = HH-1;
    int clo = fc-4; if (clo < 0) clo = 0;
    int chi = fc+4; if (chi > WW-1) chi = WW-1;
    float best = 3.4e38f; int bjg = 0;
    for (int ci = rlo; ci <= rhi; ++ci){
      for (int cj = clo; cj <= chi; ++cj){
        int cell = ci*WW + cj;
        int n = counts[cell]; if (n > SLOTS) n = SLOTS;
        for (int s = 0; s < n; ++s){
          float4 g = cells[cell*SLOTS + s];
          float rg = g.x, cg = g.y, sg = g.z;
          int jg = __float_as_int(g.w);
          float cross = fmaf(cp, cg, rp*rg);      // same bits as brute force
          float d2 = (sp + sg) - (2.0f*cross);
          d2 = fmaxf(d2, 0.0f);
          bool better = (d2 < best) || ((d2 == best) && (jg < bjg));
          if (better){ best = d2; bjg = jg; }
        }
      }
    }
    // bilinear corners
    int r0 = (int)floorf(rp); if (r0 < 0) r0 = 0; if (r0 > HH-1) r0 = HH-1;
    int c0 = (int)floorf(cp); if (c0 < 0) c0 = 0; if (c0 > WW-1) c0 = WW-1;
    int r1 = r0 + 1; if (r1 > HH-1) r1 = HH-1;
    int c1 = c0 + 1; if (c1 > WW-1) c1 = WW-1;
    float ar = rp - (float)r0, ac = cp - (float)c0;
    float omr = 1.0f - ar, omc = 1.0f - ac;
    float wa = omr*omc, wb = omr*ac, wc = ar*omc, wd = ar*ac;
    float nr = (((N[(r0*WW+c0)*2]*wa) + (N[(r0*WW+c1)*2]*wb))
               + (N[(r1*WW+c0)*2]*wc)) + (N[(r1*WW+c1)*2]*wd);
    float nc = (((N[(r0*WW+c0)*2+1]*wa) + (N[(r0*WW+c1)*2+1]*wb))
               + (N[(r1*WW+c0)*2+1]*wc)) + (N[(r1*WW+c1)*2+1]*wd);
    float nrm = sqrtf((nr*nr) + (nc*nc));
    float den = nrm + 1e-8f;
    float nru = nr / den, ncu = nc / den;
    float dr = gtR[bjg] - rp;
    float dc = gtC[bjg] - cp;
    float dotv = (dr*nru) + (dc*ncu);
    int contrib = prM[k] && (best <= 9.0f);
    dotA[k] = contrib ? dotv : 0.0f;
    float vals = (((PR[r0*WW+c0]*wa) + (PR[r0*WW+c1]*wb))
                 + (PR[r1*WW+c0]*wc)) + (PR[r1*WW+c1]*wd);
    pv = prM[k] ? (double)vals : 0.0;
  }
  for (int off = 32; off; off >>= 1) pv += __shfl_down(pv, off, 64);
  __shared__ double sb[4];
  int lane = threadIdx.x & 63, wid = threadIdx.x >> 6;
  if (lane == 0) sb[wid] = pv;
  __syncthreads();
  if (threadIdx.x == 0) atomicAdd(pixAcc, (sb[0]+sb[1])+(sb[2]+sb[3]));
}

// ---- K3: per-pixel ordered scatter replication (pred * dSDF) -------------
__global__ void k_pixel(const float* __restrict__ PR,
                        const float* __restrict__ prR, const float* __restrict__ prC,
                        const float* __restrict__ dotA, float* tmp){
#pragma clang fp contract(off)
  int p = blockIdx.x*256 + threadIdx.x;
  if (p >= NPIX) return;
  int i = p / WW, j = p % WW;
  float s = 0.0f;
  // pass1 vertical: wa = (1-ar) at (r0, j)
  for (int i0 = i-1; i0 <= i; ++i0){
    if (i0 < 0 || i0 > HH-2) continue;
    int k = i0*WW + j;
    float r = prR[k];
    int r0 = (int)floorf(r);
    if (r0 == i){
      float ar = r - (float)r0;
      float w = 1.0f - ar;
      s = s + (dotA[k] * w);
    }
  }
  // pass1 horizontal: wa = (1-ac) at (i, c0)
  for (int j0 = j-1; j0 <= j; ++j0){
    if (j0 < 0 || j0 > WW-2) continue;
    int k = NV + i*(WW-1) + j0;
    float c = prC[k];
    int c0 = (int)floorf(c);
    if (c0 == j){
      float ac = c - (float)c0;
      float w = 1.0f - ac;
      s = s + (dotA[k] * w);
    }
  }
  // pass2 horizontal: wb = ac at (i, c0+1)
  for (int j0 = j-2; j0 <= j-1; ++j0){
    if (j0 < 0 || j0 > WW-2) continue;
    int k = NV + i*(WW-1) + j0;
    float c = prC[k];
    int c0 = (int)floorf(c);
    if (c0 == j-1){
      float ac = c - (float)c0;
      s = s + (dotA[k] * ac);
    }
  }
  // pass3 vertical: wc = ar at (r0+1, j)
  for (int i0 = i-2; i0 <= i-1; ++i0){
    if (i0 < 0 || i0 > HH-2) continue;
    int k = i0*WW + j;
    float r = prR[k];
    int r0 = (int)floorf(r);
    if (r0 == i-1){
      float ar = r - (float)r0;
      s = s + (dotA[k] * ar);
    }
  }
  tmp[p] = PR[p] * s;
}

// ---- K4: numpy pairwise sum (9216 = 128 leaves x 72) + final combine ------
__global__ void k_final(const float* __restrict__ tmp, const double* __restrict__ pixAcc,
                        float* out){
#pragma clang fp contract(off)
  __shared__ float buf[128];
  int t = threadIdx.x;                 // 0..127
  const float* a = tmp + t*72;
  float r0=a[0],r1=a[1],r2=a[2],r3=a[3],r4=a[4],r5=a[5],r6=a[6],r7=a[7];
  for (int i = 8; i < 72; i += 8){
    r0 += a[i];   r1 += a[i+1]; r2 += a[i+2]; r3 += a[i+3];
    r4 += a[i+4]; r5 += a[i+5]; r6 += a[i+6]; r7 += a[i+7];
  }
  buf[t] = ((r0+r1)+(r2+r3)) + ((r4+r5)+(r6+r7));
  __syncthreads();
  for (int st = 1; st < 128; st <<= 1){
    if ((t & (2*st - 1)) == 0) buf[t] = buf[t] + buf[t+st];
    __syncthreads();
  }
  if (t == 0){
    float inj = buf[0];
    float pix = (float)(*pixAcc);
    out[0] = inj + pix;
  }
}

extern "C" void kernel_launch(void* const* d_in, const int* in_sizes, int n_in,
                              void* d_out, int out_size, void* d_ws, size_t ws_size,
                              hipStream_t stream){
  const float* pred = (const float*)d_in[0];
  const float* gt   = (const float*)d_in[1];
  float* out = (float*)d_out;

  // workspace layout
  double* pixAcc = (double*)d_ws;                       // 16B (padded)
  float4* cells  = (float4*)((char*)d_ws + 16);         // NCELL*SLOTS float4
  float*  f      = (float*)((char*)d_ws + 16 + NCELL*SLOTS*sizeof(float4));
  float* normals = f;  f += NPIX*2;
  float* prR = f;      f += NC;
  float* prC = f;      f += NC;
  float* gtR = f;      f += NC;
  float* gtC = f;      f += NC;
  float* dotA = f;     f += NC;
  float* tmp = f;      f += NPIX;
  int* prM = (int*)f;  f += NC;
  int* counts = (int*)f;

  hipMemsetAsync(counts, 0, NCELL*sizeof(int), stream);
  k_prep<<<dim3((2*NC+255)/256), dim3(256), 0, stream>>>(pred, gt, normals,
                prR, prC, prM, gtR, gtC, counts, cells, pixAcc);
  k_nndot<<<dim3((NC+255)/256), dim3(256), 0, stream>>>(pred, normals,
                prR, prC, prM, gtR, gtC, counts, cells, dotA, pixAcc);
  k_pixel<<<dim3((NPIX+255)/256), dim3(256), 0, stream>>>(pred, prR, prC, dotA, tmp);
  k_final<<<dim3(1), dim3(128), 0, stream>>>(tmp, pixAcc, out);
}

// Round 3
// 88.313 us; speedup vs baseline: 2.6389x; 1.3392x over previous
//
#include <hip/hip_runtime.h>
#include <math.h>

#pragma clang fp contract(off)

#define HH 96
#define WW 96
#define NV 9120          // 95*96 vertical candidates (== 96*95 horizontal)
#define NC 18240         // candidates per image
#define NPIX 9216
#define NCELL 9216       // 96x96 spatial hash cells
#define SLOTS 6          // max gt crossings per cell (generic case: <=2)
#define NBLK 4560        // NC/4 point-blocks for k_nndot
#define BIGF 1000000.0f

// ---- K1: normals + zero-crossing extraction (pred & gt) + gt grid insert --
__global__ void k_prep(const float* __restrict__ PR, const float* __restrict__ GT,
                       float* __restrict__ N,
                       float* prR, float* prC, int* prM,
                       float* gtR, float* gtC,
                       int* counts, float4* cells){
#pragma clang fp contract(off)
  int t = blockIdx.x*256 + threadIdx.x;
  if (t < NPIX){                       // central-difference normals of pred
    int i = t / WW, j = t % WW;
    float gr, gc;
    if (i == 0)         gr = PR[WW+j] - PR[j];
    else if (i == HH-1) gr = PR[(HH-1)*WW+j] - PR[(HH-2)*WW+j];
    else                gr = (PR[(i+1)*WW+j] - PR[(i-1)*WW+j]) / 2.0f;
    if (j == 0)         gc = PR[i*WW+1] - PR[i*WW];
    else if (j == WW-1) gc = PR[i*WW+WW-1] - PR[i*WW+WW-2];
    else                gc = (PR[i*WW+j+1] - PR[i*WW+j-1]) / 2.0f;
    N[t*2] = gr; N[t*2+1] = gc;
  }
  if (t >= 2*NC) return;
  const float* S = (t < NC) ? PR : GT;
  int u = (t < NC) ? t : t - NC;
  float v1, v2, r, c;
  if (u < NV){                         // vertical pair (i0,j)-(i0+1,j)
    int i0 = u / WW, j = u % WW;
    v1 = S[i0*WW+j]; v2 = S[(i0+1)*WW+j];
    float a1 = fabsf(v1), a2 = fabsf(v2);
    float den = (a1 + a2) + 1e-8f;     // left-assoc as reference
    float a = a1 / den;
    float i0f = (float)i0;
    r = (v1 == 0.0f) ? i0f : ((v2 == 0.0f) ? (i0f + 1.0f) : (i0f + a));
    c = (float)j;
  } else {                             // horizontal pair (i,j0)-(i,j0+1)
    int u2 = u - NV;
    int i = u2 / (WW-1), j0 = u2 % (WW-1);
    v1 = S[i*WW+j0]; v2 = S[i*WW+j0+1];
    float a1 = fabsf(v1), a2 = fabsf(v2);
    float den = (a1 + a2) + 1e-8f;
    float b = a1 / den;
    float j0f = (float)j0;
    c = (v1 == 0.0f) ? j0f : ((v2 == 0.0f) ? (j0f + 1.0f) : (j0f + b));
    r = (float)i;
  }
  int m = (v1 == 0.0f) || (v2 == 0.0f) || ((v1*v2) < 0.0f);
  if (t < NC){ prR[u] = r; prC[u] = c; prM[u] = m; }
  else {
    float gr = m ? r : BIGF;
    float gc = m ? c : BIGF;
    gtR[u] = gr; gtC[u] = gc;
    if (m){                            // insert into spatial grid
      int fr = (int)floorf(r); if (fr < 0) fr = 0; if (fr > HH-1) fr = HH-1;
      int fc = (int)floorf(c); if (fc < 0) fc = 0; if (fc > WW-1) fc = WW-1;
      int cell = fr*WW + fc;
      int slot = atomicAdd(&counts[cell], 1);
      if (slot < SLOTS){
        float sg = (r*r) + (c*c);      // matches (gp**2).sum(1)
        cells[cell*SLOTS + slot] = make_float4(r, c, sg, __int_as_float(u));
      }
    }
  }
}

// ---- K2: wave-per-point grid NN (lex (d2,jg) min == numpy first argmin) ---
//      lanes split the 9x9 cell window; butterfly reduce; lane0 epilogue
__global__ __launch_bounds__(256) void k_nndot(
    const float* __restrict__ PR, const float* __restrict__ N,
    const float* __restrict__ prR, const float* __restrict__ prC,
    const int* __restrict__ prM,
    const float* __restrict__ gtR, const float* __restrict__ gtC,
    const int* __restrict__ counts, const float4* __restrict__ cells,
    float* dotA, double* pvPart){
#pragma clang fp contract(off)
  int lane = threadIdx.x & 63, wid = threadIdx.x >> 6;
  int k = blockIdx.x*4 + wid;          // grid is exactly NC/4 blocks
  float rp = prR[k], cp = prC[k];
  float sp = (rp*rp) + (cp*cp);        // matches (pr_pts**2).sum(1)
  int fr = (int)floorf(rp), fc = (int)floorf(cp);
  float best = 3.4e38f; int bjg = 0x7fffffff;
  for (int idx = lane; idx < 81; idx += 64){
    int ci = fr + idx/9 - 4;
    int cj = fc + idx%9 - 4;
    if (ci >= 0 && ci < HH && cj >= 0 && cj < WW){
      int cell = ci*WW + cj;
      int n = counts[cell]; if (n > SLOTS) n = SLOTS;
      for (int s = 0; s < n; ++s){
        float4 g = cells[cell*SLOTS + s];
        float cross = fmaf(cp, g.y, rp*g.x);   // same bits as brute force
        float d2 = (sp + g.z) - (2.0f*cross);
        d2 = fmaxf(d2, 0.0f);
        int jg = __float_as_int(g.w);
        if ((d2 < best) || ((d2 == best) && (jg < bjg))){ best = d2; bjg = jg; }
      }
    }
  }
  for (int off = 32; off; off >>= 1){   // lexicographic butterfly reduce
    float ob = __shfl_xor(best, off, 64);
    int   oj = __shfl_xor(bjg,  off, 64);
    if ((ob < best) || ((ob == best) && (oj < bjg))){ best = ob; bjg = oj; }
  }
  __shared__ double sb[4];
  if (lane == 0){
    if (bjg < 0 || bjg > NC-1) bjg = 0;    // empty-window safety (contrib=0)
    int r0 = (int)floorf(rp); if (r0 < 0) r0 = 0; if (r0 > HH-1) r0 = HH-1;
    int c0 = (int)floorf(cp); if (c0 < 0) c0 = 0; if (c0 > WW-1) c0 = WW-1;
    int r1 = r0 + 1; if (r1 > HH-1) r1 = HH-1;
    int c1 = c0 + 1; if (c1 > WW-1) c1 = WW-1;
    float ar = rp - (float)r0, ac = cp - (float)c0;
    float omr = 1.0f - ar, omc = 1.0f - ac;
    float wa = omr*omc, wb = omr*ac, wc = ar*omc, wd = ar*ac;
    float nr = (((N[(r0*WW+c0)*2]*wa) + (N[(r0*WW+c1)*2]*wb))
               + (N[(r1*WW+c0)*2]*wc)) + (N[(r1*WW+c1)*2]*wd);
    float nc = (((N[(r0*WW+c0)*2+1]*wa) + (N[(r0*WW+c1)*2+1]*wb))
               + (N[(r1*WW+c0)*2+1]*wc)) + (N[(r1*WW+c1)*2+1]*wd);
    float nrm = sqrtf((nr*nr) + (nc*nc));
    float den = nrm + 1e-8f;
    float nru = nr / den, ncu = nc / den;
    float dr = gtR[bjg] - rp;
    float dc = gtC[bjg] - cp;
    float dotv = (dr*nru) + (dc*ncu);
    int m = prM[k];
    int contrib = m && (best <= 9.0f);
    dotA[k] = contrib ? dotv : 0.0f;
    float vals = (((PR[r0*WW+c0]*wa) + (PR[r0*WW+c1]*wb))
                 + (PR[r1*WW+c0]*wc)) + (PR[r1*WW+c1]*wd);
    sb[wid] = m ? (double)vals : 0.0;
  }
  __syncthreads();
  if (threadIdx.x == 0) pvPart[blockIdx.x] = (sb[0]+sb[1])+(sb[2]+sb[3]);
}

// ---- K3: per-pixel ordered scatter replication (pred * dSDF) -------------
__global__ __launch_bounds__(64) void k_pixel(const float* __restrict__ PR,
                        const float* __restrict__ prR, const float* __restrict__ prC,
                        const float* __restrict__ dotA, float* tmp){
#pragma clang fp contract(off)
  int p = blockIdx.x*64 + threadIdx.x;
  if (p >= NPIX) return;
  int i = p / WW, j = p % WW;
  float s = 0.0f;
  // pass1 vertical: wa = (1-ar) at (r0, j)
  for (int i0 = i-1; i0 <= i; ++i0){
    if (i0 < 0 || i0 > HH-2) continue;
    int k = i0*WW + j;
    float r = prR[k];
    int r0 = (int)floorf(r);
    if (r0 == i){
      float ar = r - (float)r0;
      float w = 1.0f - ar;
      s = s + (dotA[k] * w);
    }
  }
  // pass1 horizontal: wa = (1-ac) at (i, c0)
  for (int j0 = j-1; j0 <= j; ++j0){
    if (j0 < 0 || j0 > WW-2) continue;
    int k = NV + i*(WW-1) + j0;
    float c = prC[k];
    int c0 = (int)floorf(c);
    if (c0 == j){
      float ac = c - (float)c0;
      float w = 1.0f - ac;
      s = s + (dotA[k] * w);
    }
  }
  // pass2 horizontal: wb = ac at (i, c0+1)
  for (int j0 = j-2; j0 <= j-1; ++j0){
    if (j0 < 0 || j0 > WW-2) continue;
    int k = NV + i*(WW-1) + j0;
    float c = prC[k];
    int c0 = (int)floorf(c);
    if (c0 == j-1){
      float ac = c - (float)c0;
      s = s + (dotA[k] * ac);
    }
  }
  // pass3 vertical: wc = ar at (r0+1, j)
  for (int i0 = i-2; i0 <= i-1; ++i0){
    if (i0 < 0 || i0 > HH-2) continue;
    int k = i0*WW + j;
    float r = prR[k];
    int r0 = (int)floorf(r);
    if (r0 == i-1){
      float ar = r - (float)r0;
      s = s + (dotA[k] * ar);
    }
  }
  tmp[p] = PR[p] * s;
}

// ---- K4: numpy pairwise sum (128 leaves x 72, float4 loads, same order) ---
//          + double sum of pix partials
__global__ void k_final(const float* __restrict__ tmp,
                        const double* __restrict__ pvPart, float* out){
#pragma clang fp contract(off)
  __shared__ float buf[128];
  __shared__ double dbuf[128];
  int t = threadIdx.x;                 // 0..127
  const float4* a4 = (const float4*)(tmp + t*72);   // 288B offset: 16B aligned
  float4 x = a4[0], y = a4[1];
  float r0=x.x, r1=x.y, r2=x.z, r3=x.w, r4=y.x, r5=y.y, r6=y.z, r7=y.w;
  for (int i4 = 2; i4 < 18; i4 += 2){
    float4 u = a4[i4], v = a4[i4+1];
    r0 += u.x; r1 += u.y; r2 += u.z; r3 += u.w;
    r4 += v.x; r5 += v.y; r6 += v.z; r7 += v.w;
  }
  buf[t] = ((r0+r1)+(r2+r3)) + ((r4+r5)+(r6+r7));
  double pv = 0.0;
  for (int i = t; i < NBLK; i += 128) pv += pvPart[i];
  dbuf[t] = pv;
  __syncthreads();
  for (int st = 1; st < 128; st <<= 1){
    if ((t & (2*st - 1)) == 0){
      buf[t]  = buf[t]  + buf[t+st];
      dbuf[t] = dbuf[t] + dbuf[t+st];
    }
    __syncthreads();
  }
  if (t == 0){
    float inj = buf[0];
    float pix = (float)dbuf[0];
    out[0] = inj + pix;
  }
}

extern "C" void kernel_launch(void* const* d_in, const int* in_sizes, int n_in,
                              void* d_out, int out_size, void* d_ws, size_t ws_size,
                              hipStream_t stream){
  const float* pred = (const float*)d_in[0];
  const float* gt   = (const float*)d_in[1];
  float* out = (float*)d_out;

  // workspace layout
  float4* cells  = (float4*)((char*)d_ws + 16);               // NCELL*SLOTS
  double* pvPart = (double*)((char*)d_ws + 16 + (size_t)NCELL*SLOTS*sizeof(float4));
  float*  f      = (float*)(pvPart + NBLK);
  float* normals = f;  f += NPIX*2;
  float* prR = f;      f += NC;
  float* prC = f;      f += NC;
  float* gtR = f;      f += NC;
  float* gtC = f;      f += NC;
  float* dotA = f;     f += NC;
  float* tmp = f;      f += NPIX;
  int* prM = (int*)f;  f += NC;
  int* counts = (int*)f;

  hipMemsetAsync(counts, 0, NCELL*sizeof(int), stream);
  k_prep<<<dim3((2*NC+255)/256), dim3(256), 0, stream>>>(pred, gt, normals,
                prR, prC, prM, gtR, gtC, counts, cells);
  k_nndot<<<dim3(NBLK), dim3(256), 0, stream>>>(pred, normals,
                prR, prC, prM, gtR, gtC, counts, cells, dotA, pvPart);
  k_pixel<<<dim3((NPIX+63)/64), dim3(64), 0, stream>>>(pred, prR, prC, dotA, tmp);
  k_final<<<dim3(1), dim3(128), 0, stream>>>(tmp, pvPart, out);
}

// Round 4
// 84.649 us; speedup vs baseline: 2.7531x; 1.0433x over previous
//
#include <hip/hip_runtime.h>
#include <math.h>

#pragma clang fp contract(off)

#define HH 96
#define WW 96
#define NV 9120          // 95*96 vertical candidates (== 96*95 horizontal)
#define NC 18240         // candidates per image
#define NPIX 9216
#define NCELL 9216       // 96x96 spatial hash cells
#define SLOTS 4          // deterministic bound: <=4 gt crossings per cell
#define NBLK 4560        // NC/4 point-blocks for k_nndot
#define PBLK 72          // 9216/128 pixel blocks
#define BIGF 1000000.0f

// ---- K1: normals + pred extraction + deterministic atomic-free grid build -
__global__ __launch_bounds__(256) void k_prep(
    const float* __restrict__ PR, const float* __restrict__ GT,
    float2* __restrict__ N2, float* prR, float* prC, int* prM,
    int* counts, float4* cells, int* finCnt){
#pragma clang fp contract(off)
  int t = blockIdx.x*256 + threadIdx.x;
  if (t == 0) *finCnt = 0;
  if (t < NPIX){
    int i = t / WW, j = t % WW;
    // central-difference normals of pred
    float gr, gc;
    if (i == 0)         gr = PR[WW+j] - PR[j];
    else if (i == HH-1) gr = PR[(HH-1)*WW+j] - PR[(HH-2)*WW+j];
    else                gr = (PR[(i+1)*WW+j] - PR[(i-1)*WW+j]) / 2.0f;
    if (j == 0)         gc = PR[i*WW+1] - PR[i*WW];
    else if (j == WW-1) gc = PR[i*WW+WW-1] - PR[i*WW+WW-2];
    else                gc = (PR[i*WW+j+1] - PR[i*WW+j-1]) / 2.0f;
    N2[t] = make_float2(gr, gc);
    // grid build for cell (i,j): <=4 deterministic sources
    int cnt = 0;
    for (int s = 0; s < 2; ++s){              // vertical sources i0=i-1, i
      int i0 = i - 1 + s;
      if (i0 >= 0 && i0 <= HH-2){
        float v1 = GT[i0*WW+j], v2 = GT[(i0+1)*WW+j];
        int m = (v1 == 0.0f) || (v2 == 0.0f) || ((v1*v2) < 0.0f);
        if (m){
          float a1 = fabsf(v1), a2 = fabsf(v2);
          float den = (a1 + a2) + 1e-8f;      // left-assoc as reference
          float a = a1 / den;
          float i0f = (float)i0;
          float r = (v1 == 0.0f) ? i0f : ((v2 == 0.0f) ? (i0f + 1.0f) : (i0f + a));
          if ((int)floorf(r) == i){           // lands in this cell row
            float c = (float)j;
            float sg = (r*r) + (c*c);         // matches (gp**2).sum(1)
            cells[t*SLOTS + cnt] = make_float4(r, c, sg, __int_as_float(i0*WW+j));
            cnt++;
          }
        }
      }
    }
    for (int s = 0; s < 2; ++s){              // horizontal sources j0=j-1, j
      int j0 = j - 1 + s;
      if (j0 >= 0 && j0 <= WW-2){
        float v1 = GT[i*WW+j0], v2 = GT[i*WW+j0+1];
        int m = (v1 == 0.0f) || (v2 == 0.0f) || ((v1*v2) < 0.0f);
        if (m){
          float a1 = fabsf(v1), a2 = fabsf(v2);
          float den = (a1 + a2) + 1e-8f;
          float b = a1 / den;
          float j0f = (float)j0;
          float c = (v1 == 0.0f) ? j0f : ((v2 == 0.0f) ? (j0f + 1.0f) : (j0f + b));
          if ((int)floorf(c) == j){           // lands in this cell col
            float r = (float)i;
            float sg = (r*r) + (c*c);
            cells[t*SLOTS + cnt] = make_float4(r, c, sg,
                                     __int_as_float(NV + i*(WW-1) + j0));
            cnt++;
          }
        }
      }
    }
    counts[t] = cnt;
  }
  if (t < NC){                                // pred extraction (as before)
    float v1, v2, r, c;
    if (t < NV){
      int i0 = t / WW, j = t % WW;
      v1 = PR[i0*WW+j]; v2 = PR[(i0+1)*WW+j];
      float a1 = fabsf(v1), a2 = fabsf(v2);
      float den = (a1 + a2) + 1e-8f;
      float a = a1 / den;
      float i0f = (float)i0;
      r = (v1 == 0.0f) ? i0f : ((v2 == 0.0f) ? (i0f + 1.0f) : (i0f + a));
      c = (float)j;
    } else {
      int u2 = t - NV;
      int i = u2 / (WW-1), j0 = u2 % (WW-1);
      v1 = PR[i*WW+j0]; v2 = PR[i*WW+j0+1];
      float a1 = fabsf(v1), a2 = fabsf(v2);
      float den = (a1 + a2) + 1e-8f;
      float b = a1 / den;
      float j0f = (float)j0;
      c = (v1 == 0.0f) ? j0f : ((v2 == 0.0f) ? (j0f + 1.0f) : (j0f + b));
      r = (float)i;
    }
    prR[t] = r; prC[t] = c;
    prM[t] = (v1 == 0.0f) || (v2 == 0.0f) || ((v1*v2) < 0.0f);
  }
}

// ring offset for chebyshev ring R, perimeter index q in [0, 8R)
__device__ inline void ring_off(int R, int q, int& dr, int& dc){
  int side = 2*R + 1;
  if (q < side){ dr = -R; dc = q - R; }
  else if (q < 2*side){ dr = R; dc = q - side - R; }
  else {
    int q2 = q - 2*side, half = side - 2;
    if (q2 < half){ dr = q2 - R + 1; dc = -R; }
    else          { dr = q2 - half - R + 1; dc = R; }
  }
}

// ---- K2: wave-per-point NN with ring early-exit; all-lane epilogue --------
__global__ __launch_bounds__(256) void k_nndot(
    const float* __restrict__ PR, const float2* __restrict__ N2,
    const float* __restrict__ prR, const float* __restrict__ prC,
    const int* __restrict__ prM,
    const int* __restrict__ counts, const float4* __restrict__ cells,
    float* dotA, double* pvPart){
#pragma clang fp contract(off)
  int lane = threadIdx.x & 63, wid = threadIdx.x >> 6;
  int k = blockIdx.x*4 + wid;
  float rp = prR[k], cp = prC[k];
  int m = prM[k];
  // corner prefetch (wave-uniform addresses -> broadcast loads, issued early)
  int r0 = (int)floorf(rp); if (r0 < 0) r0 = 0; if (r0 > HH-1) r0 = HH-1;
  int c0 = (int)floorf(cp); if (c0 < 0) c0 = 0; if (c0 > WW-1) c0 = WW-1;
  int r1 = r0 + 1; if (r1 > HH-1) r1 = HH-1;
  int c1 = c0 + 1; if (c1 > WW-1) c1 = WW-1;
  float2 na = N2[r0*WW+c0], nb = N2[r0*WW+c1];
  float2 ncn = N2[r1*WW+c0], nd = N2[r1*WW+c1];
  float pa = PR[r0*WW+c0], pb = PR[r0*WW+c1];
  float pc = PR[r1*WW+c0], pd = PR[r1*WW+c1];
  float sp = (rp*rp) + (cp*cp);        // matches (pr_pts**2).sum(1)
  int fr = (int)floorf(rp), fc = (int)floorf(cp);
  float best = 3.4e38f, brg = 0.0f, bcg = 0.0f; int bjg = 0x7fffffff;
  // phase 1: inner 5x5 (radius 2), one cell per lane
  if (lane < 25){
    int ci = fr + lane/5 - 2, cj = fc + lane%5 - 2;
    if (ci >= 0 && ci < HH && cj >= 0 && cj < WW){
      int cell = ci*WW + cj;
      int n = counts[cell]; if (n > SLOTS) n = SLOTS;
      for (int s = 0; s < n; ++s){
        float4 g = cells[cell*SLOTS + s];
        float cross = fmaf(cp, g.y, rp*g.x);     // same bits as brute force
        float d2 = (sp + g.z) - (2.0f*cross);
        d2 = fmaxf(d2, 0.0f);
        int jg = __float_as_int(g.w);
        if ((d2 < best) || ((d2 == best) && (jg < bjg))){
          best = d2; bjg = jg; brg = g.x; bcg = g.y;
        }
      }
    }
  }
  for (int off = 32; off; off >>= 1){    // lexicographic butterfly reduce
    float ob = __shfl_xor(best, off, 64);
    int   oj = __shfl_xor(bjg,  off, 64);
    float orr = __shfl_xor(brg, off, 64);
    float oc = __shfl_xor(bcg, off, 64);
    if ((ob < best) || ((ob == best) && (oj < bjg))){
      best = ob; bjg = oj; brg = orr; bcg = oc;
    }
  }
  // any point outside radius 2 has true d2 > 4 (computed >= 4-6e-6):
  // if best <= 3.9999 the outer ring can neither beat nor tie -> skip.
  if (best > 3.9999f){                   // wave-uniform after reduce
    if (lane < 56){                      // rings 3 (24) + 4 (32)
      int dr2, dc2;
      if (lane < 24) ring_off(3, lane, dr2, dc2);
      else           ring_off(4, lane-24, dr2, dc2);
      int ci = fr + dr2, cj = fc + dc2;
      if (ci >= 0 && ci < HH && cj >= 0 && cj < WW){
        int cell = ci*WW + cj;
        int n = counts[cell]; if (n > SLOTS) n = SLOTS;
        for (int s = 0; s < n; ++s){
          float4 g = cells[cell*SLOTS + s];
          float cross = fmaf(cp, g.y, rp*g.x);
          float d2 = (sp + g.z) - (2.0f*cross);
          d2 = fmaxf(d2, 0.0f);
          int jg = __float_as_int(g.w);
          if ((d2 < best) || ((d2 == best) && (jg < bjg))){
            best = d2; bjg = jg; brg = g.x; bcg = g.y;
          }
        }
      }
    }
    for (int off = 32; off; off >>= 1){
      float ob = __shfl_xor(best, off, 64);
      int   oj = __shfl_xor(bjg,  off, 64);
      float orr = __shfl_xor(brg, off, 64);
      float oc = __shfl_xor(bcg, off, 64);
      if ((ob < best) || ((ob == best) && (oj < bjg))){
        best = ob; bjg = oj; brg = orr; bcg = oc;
      }
    }
  }
  // epilogue: all lanes redundantly (no divergence), lane0 stores
  float ar = rp - (float)r0, ac = cp - (float)c0;
  float omr = 1.0f - ar, omc = 1.0f - ac;
  float wa = omr*omc, wb = omr*ac, wc = ar*omc, wd = ar*ac;
  float nr = (((na.x*wa) + (nb.x*wb)) + (ncn.x*wc)) + (nd.x*wd);
  float nc = (((na.y*wa) + (nb.y*wb)) + (ncn.y*wc)) + (nd.y*wd);
  float nrm = sqrtf((nr*nr) + (nc*nc));
  float den = nrm + 1e-8f;
  float nru = nr / den, ncu = nc / den;
  float dr = brg - rp, dc = bcg - cp;    // winner's (r,c) carried in-register
  float dotv = (dr*nru) + (dc*ncu);
  int contrib = m && (best <= 9.0f);
  float vals = (((pa*wa) + (pb*wb)) + (pc*wc)) + (pd*wd);
  __shared__ double sb[4];
  if (lane == 0){
    dotA[k] = contrib ? dotv : 0.0f;
    sb[wid] = m ? (double)vals : 0.0;
  }
  __syncthreads();
  if (threadIdx.x == 0) pvPart[blockIdx.x] = (sb[0]+sb[1])+(sb[2]+sb[3]);
}

// ---- K3: ordered scatter replication + fused last-block final reduction ---
__global__ __launch_bounds__(128) void k_pixfinal(
    const float* __restrict__ PR,
    const float* __restrict__ prR, const float* __restrict__ prC,
    const float* __restrict__ dotA, const double* __restrict__ pvPart,
    float* tmp, int* finCnt, float* out){
#pragma clang fp contract(off)
  int p = blockIdx.x*128 + threadIdx.x;   // exactly NPIX threads
  int i = p / WW, j = p % WW;
  float s = 0.0f;
  // pass1 vertical: wa = (1-ar) at (r0, j)
  for (int i0 = i-1; i0 <= i; ++i0){
    if (i0 < 0 || i0 > HH-2) continue;
    int k = i0*WW + j;
    float r = prR[k];
    int r0 = (int)floorf(r);
    if (r0 == i){
      float ar = r - (float)r0;
      float w = 1.0f - ar;
      s = s + (dotA[k] * w);
    }
  }
  // pass1 horizontal: wa = (1-ac) at (i, c0)
  for (int j0 = j-1; j0 <= j; ++j0){
    if (j0 < 0 || j0 > WW-2) continue;
    int k = NV + i*(WW-1) + j0;
    float c = prC[k];
    int c0 = (int)floorf(c);
    if (c0 == j){
      float ac = c - (float)c0;
      float w = 1.0f - ac;
      s = s + (dotA[k] * w);
    }
  }
  // pass2 horizontal: wb = ac at (i, c0+1)
  for (int j0 = j-2; j0 <= j-1; ++j0){
    if (j0 < 0 || j0 > WW-2) continue;
    int k = NV + i*(WW-1) + j0;
    float c = prC[k];
    int c0 = (int)floorf(c);
    if (c0 == j-1){
      float ac = c - (float)c0;
      s = s + (dotA[k] * ac);
    }
  }
  // pass3 vertical: wc = ar at (r0+1, j)
  for (int i0 = i-2; i0 <= i-1; ++i0){
    if (i0 < 0 || i0 > HH-2) continue;
    int k = i0*WW + j;
    float r = prR[k];
    int r0 = (int)floorf(r);
    if (r0 == i-1){
      float ar = r - (float)r0;
      s = s + (dotA[k] * ar);
    }
  }
  tmp[p] = PR[p] * s;
  // release our tmp writes, count this block done
  __threadfence();
  __syncthreads();
  __shared__ int lastFlag;
  if (threadIdx.x == 0){
    int old = atomicAdd(finCnt, 1);      // device-scope
    lastFlag = (old == PBLK-1);
  }
  __syncthreads();
  if (!lastFlag) return;
  __threadfence();                       // acquire: see all blocks' tmp
  // numpy pairwise sum (128 leaves x 72, identical order) + pix double sum
  __shared__ float buf[128];
  __shared__ double dbuf[128];
  int t = threadIdx.x;
  const float4* a4 = (const float4*)(tmp + t*72);
  float4 x = a4[0], y = a4[1];
  float q0=x.x, q1=x.y, q2=x.z, q3=x.w, q4=y.x, q5=y.y, q6=y.z, q7=y.w;
  for (int i4 = 2; i4 < 18; i4 += 2){
    float4 u = a4[i4], v = a4[i4+1];
    q0 += u.x; q1 += u.y; q2 += u.z; q3 += u.w;
    q4 += v.x; q5 += v.y; q6 += v.z; q7 += v.w;
  }
  buf[t] = ((q0+q1)+(q2+q3)) + ((q4+q5)+(q6+q7));
  double pv = 0.0;
  for (int idx = t; idx < NBLK; idx += 128) pv += pvPart[idx];
  dbuf[t] = pv;
  __syncthreads();
  for (int st = 1; st < 128; st <<= 1){
    if ((t & (2*st - 1)) == 0){
      buf[t]  = buf[t]  + buf[t+st];
      dbuf[t] = dbuf[t] + dbuf[t+st];
    }
    __syncthreads();
  }
  if (t == 0) out[0] = buf[0] + (float)dbuf[0];
}

extern "C" void kernel_launch(void* const* d_in, const int* in_sizes, int n_in,
                              void* d_out, int out_size, void* d_ws, size_t ws_size,
                              hipStream_t stream){
  const float* pred = (const float*)d_in[0];
  const float* gt   = (const float*)d_in[1];
  float* out = (float*)d_out;

  char* w = (char*)d_ws;
  float4* cells  = (float4*)w;                 w += (size_t)NCELL*SLOTS*sizeof(float4); // 589824
  double* pvPart = (double*)w;                 w += (size_t)NBLK*sizeof(double);        // 36480
  float2* N2     = (float2*)w;                 w += (size_t)NPIX*sizeof(float2);        // 73728
  float*  prR    = (float*)w;                  w += (size_t)NC*sizeof(float);
  float*  prC    = (float*)w;                  w += (size_t)NC*sizeof(float);
  float*  dotA   = (float*)w;                  w += (size_t)NC*sizeof(float);
  float*  tmp    = (float*)w;                  w += (size_t)NPIX*sizeof(float);
  int*    prM    = (int*)w;                    w += (size_t)NC*sizeof(int);
  int*    counts = (int*)w;                    w += (size_t)NCELL*sizeof(int);
  int*    finCnt = (int*)w;

  k_prep<<<dim3(72), dim3(256), 0, stream>>>(pred, gt, N2, prR, prC, prM,
                                             counts, cells, finCnt);
  k_nndot<<<dim3(NBLK), dim3(256), 0, stream>>>(pred, N2, prR, prC, prM,
                                                counts, cells, dotA, pvPart);
  k_pixfinal<<<dim3(PBLK), dim3(128), 0, stream>>>(pred, prR, prC, dotA,
                                                   pvPart, tmp, finCnt, out);
}

// Round 5
// 75.787 us; speedup vs baseline: 3.0751x; 1.1169x over previous
//
#include <hip/hip_runtime.h>
#include <math.h>

#pragma clang fp contract(off)

#define HH 96
#define WW 96
#define NV 9120          // 95*96 vertical candidates (== 96*95 horizontal)
#define NC 18240         // candidates per image
#define NPIX 9216
#define NCELL 9216       // 96x96 spatial hash cells
#define SLOTS 4          // deterministic bound: <=4 gt crossings per cell
#define NBLK2 1140       // NC/16 point-blocks for k_nndot (16 lanes/point)
#define PBLK 72          // 9216/128 pixel blocks
#define BIGF 1000000.0f
#define SENT_D 3.4e38f
#define SENT_J 0x7fffffff

// ---- K1: split work items: [0,NPIX) normals+grid, [NPIX,NPIX+NC) pred ----
__global__ __launch_bounds__(256) void k_prep(
    const float* __restrict__ PR, const float* __restrict__ GT,
    float2* __restrict__ N2, float2* prP, int* prM,
    float4* cells, int* finCnt){
#pragma clang fp contract(off)
  int t = blockIdx.x*256 + threadIdx.x;
  if (t == 0) *finCnt = 0;
  if (t < NPIX){
    int i = t / WW, j = t % WW;
    // central-difference normals of pred
    float gr, gc;
    if (i == 0)         gr = PR[WW+j] - PR[j];
    else if (i == HH-1) gr = PR[(HH-1)*WW+j] - PR[(HH-2)*WW+j];
    else                gr = (PR[(i+1)*WW+j] - PR[(i-1)*WW+j]) / 2.0f;
    if (j == 0)         gc = PR[i*WW+1] - PR[i*WW];
    else if (j == WW-1) gc = PR[i*WW+WW-1] - PR[i*WW+WW-2];
    else                gc = (PR[i*WW+j+1] - PR[i*WW+j-1]) / 2.0f;
    N2[t] = make_float2(gr, gc);
    // grid build for cell (i,j): <=4 deterministic sources, sentinel-padded
    int cnt = 0;
    float4 slot[SLOTS];
    for (int s = 0; s < 2; ++s){              // vertical sources i0=i-1, i
      int i0 = i - 1 + s;
      if (i0 >= 0 && i0 <= HH-2){
        float v1 = GT[i0*WW+j], v2 = GT[(i0+1)*WW+j];
        int m = (v1 == 0.0f) || (v2 == 0.0f) || ((v1*v2) < 0.0f);
        if (m){
          float a1 = fabsf(v1), a2 = fabsf(v2);
          float den = (a1 + a2) + 1e-8f;      // left-assoc as reference
          float a = a1 / den;
          float i0f = (float)i0;
          float r = (v1 == 0.0f) ? i0f : ((v2 == 0.0f) ? (i0f + 1.0f) : (i0f + a));
          if ((int)floorf(r) == i){           // lands in this cell row
            float c = (float)j;
            float sg = (r*r) + (c*c);         // matches (gp**2).sum(1)
            slot[cnt++] = make_float4(r, c, sg, __int_as_float(i0*WW+j));
          }
        }
      }
    }
    for (int s = 0; s < 2; ++s){              // horizontal sources j0=j-1, j
      int j0 = j - 1 + s;
      if (j0 >= 0 && j0 <= WW-2){
        float v1 = GT[i*WW+j0], v2 = GT[i*WW+j0+1];
        int m = (v1 == 0.0f) || (v2 == 0.0f) || ((v1*v2) < 0.0f);
        if (m){
          float a1 = fabsf(v1), a2 = fabsf(v2);
          float den = (a1 + a2) + 1e-8f;
          float b = a1 / den;
          float j0f = (float)j0;
          float c = (v1 == 0.0f) ? j0f : ((v2 == 0.0f) ? (j0f + 1.0f) : (j0f + b));
          if ((int)floorf(c) == j){           // lands in this cell col
            float r = (float)i;
            float sg = (r*r) + (c*c);
            slot[cnt++] = make_float4(r, c, sg,
                            __int_as_float(NV + i*(WW-1) + j0));
          }
        }
      }
    }
    for (int s = cnt; s < SLOTS; ++s)         // sentinels: never win, never tie
      slot[s] = make_float4(0.0f, 0.0f, SENT_D, __int_as_float(SENT_J));
    cells[t*SLOTS+0] = slot[0]; cells[t*SLOTS+1] = slot[1];
    cells[t*SLOTS+2] = slot[2]; cells[t*SLOTS+3] = slot[3];
  } else if (t < NPIX + NC){                  // pred extraction
    int u = t - NPIX;
    float v1, v2, r, c;
    if (u < NV){
      int i0 = u / WW, j = u % WW;
      v1 = PR[i0*WW+j]; v2 = PR[(i0+1)*WW+j];
      float a1 = fabsf(v1), a2 = fabsf(v2);
      float den = (a1 + a2) + 1e-8f;
      float a = a1 / den;
      float i0f = (float)i0;
      r = (v1 == 0.0f) ? i0f : ((v2 == 0.0f) ? (i0f + 1.0f) : (i0f + a));
      c = (float)j;
    } else {
      int u2 = u - NV;
      int i = u2 / (WW-1), j0 = u2 % (WW-1);
      v1 = PR[i*WW+j0]; v2 = PR[i*WW+j0+1];
      float a1 = fabsf(v1), a2 = fabsf(v2);
      float den = (a1 + a2) + 1e-8f;
      float b = a1 / den;
      float j0f = (float)j0;
      c = (v1 == 0.0f) ? j0f : ((v2 == 0.0f) ? (j0f + 1.0f) : (j0f + b));
      r = (float)i;
    }
    prP[u] = make_float2(r, c);
    prM[u] = (v1 == 0.0f) || (v2 == 0.0f) || ((v1*v2) < 0.0f);
  }
}

// ring offset for chebyshev ring R, perimeter index q in [0, 8R)
__device__ inline void ring_off(int R, int q, int& dr, int& dc){
  int side = 2*R + 1;
  if (q < side){ dr = -R; dc = q - R; }
  else if (q < 2*side){ dr = R; dc = q - side - R; }
  else {
    int q2 = q - 2*side, half = side - 2;
    if (q2 < half){ dr = q2 - R + 1; dc = -R; }
    else          { dr = q2 - half - R + 1; dc = R; }
  }
}

// ---- K2: 16-lane-group-per-point NN, sentinel slots (no counts load) ------
__global__ __launch_bounds__(256) void k_nndot(
    const float* __restrict__ PR, const float2* __restrict__ N2,
    const float2* __restrict__ prP, const int* __restrict__ prM,
    const float4* __restrict__ cells,
    float* dotA, double* pvPart){
#pragma clang fp contract(off)
  int tid = threadIdx.x;
  int g = tid >> 4, l = tid & 15;      // 16 groups/block, 16 lanes/group
  int k = blockIdx.x*16 + g;           // grid is exactly NC/16 blocks
  float2 pp = prP[k];
  float rp = pp.x, cp = pp.y;
  int m = prM[k];
  // corner prefetch (group-uniform addresses)
  int r0 = (int)floorf(rp); if (r0 < 0) r0 = 0; if (r0 > HH-1) r0 = HH-1;
  int c0 = (int)floorf(cp); if (c0 < 0) c0 = 0; if (c0 > WW-1) c0 = WW-1;
  int r1 = r0 + 1; if (r1 > HH-1) r1 = HH-1;
  int c1 = c0 + 1; if (c1 > WW-1) c1 = WW-1;
  float2 na = N2[r0*WW+c0], nb = N2[r0*WW+c1];
  float2 ncn = N2[r1*WW+c0], nd = N2[r1*WW+c1];
  float pa = PR[r0*WW+c0], pb = PR[r0*WW+c1];
  float pc = PR[r1*WW+c0], pd = PR[r1*WW+c1];
  float sp = (rp*rp) + (cp*cp);        // matches (pr_pts**2).sum(1)
  int fr = (int)floorf(rp), fc = (int)floorf(cp);
  float best = SENT_D, brg = 0.0f, bcg = 0.0f; int bjg = SENT_J;
  // phase 1: inner 5x5 (radius 2), cells l and l+16 per lane
  for (int idx = l; idx < 25; idx += 16){
    int ci = fr + idx/5 - 2, cj = fc + idx%5 - 2;
    if (ci >= 0 && ci < HH && cj >= 0 && cj < WW){
      const float4* cb = &cells[(ci*WW + cj)*SLOTS];
      for (int s = 0; s < SLOTS; ++s){        // unconditional: sentinels inert
        float4 gg = cb[s];
        float cross = fmaf(cp, gg.y, rp*gg.x);     // same bits as brute force
        float d2 = (sp + gg.z) - (2.0f*cross);
        d2 = fmaxf(d2, 0.0f);
        int jg = __float_as_int(gg.w);
        if ((d2 < best) || ((d2 == best) && (jg < bjg))){
          best = d2; bjg = jg; brg = gg.x; bcg = gg.y;
        }
      }
    }
  }
  for (int off = 8; off; off >>= 1){   // lex butterfly within 16-lane group
    float ob = __shfl_xor(best, off, 64);
    int   oj = __shfl_xor(bjg,  off, 64);
    float orr = __shfl_xor(brg, off, 64);
    float oc = __shfl_xor(bcg, off, 64);
    if ((ob < best) || ((ob == best) && (oj < bjg))){
      best = ob; bjg = oj; brg = orr; bcg = oc;
    }
  }
  // outside radius 2 true d2 > 4 (computed >= 4-6e-6): skip if best <= 3.9999
  if (best > 3.9999f){                 // group-uniform after reduce
    for (int q = l; q < 56; q += 16){  // rings 3 (24) + 4 (32)
      int dr2, dc2;
      if (q < 24) ring_off(3, q, dr2, dc2);
      else        ring_off(4, q-24, dr2, dc2);
      int ci = fr + dr2, cj = fc + dc2;
      if (ci >= 0 && ci < HH && cj >= 0 && cj < WW){
        const float4* cb = &cells[(ci*WW + cj)*SLOTS];
        for (int s = 0; s < SLOTS; ++s){
          float4 gg = cb[s];
          float cross = fmaf(cp, gg.y, rp*gg.x);
          float d2 = (sp + gg.z) - (2.0f*cross);
          d2 = fmaxf(d2, 0.0f);
          int jg = __float_as_int(gg.w);
          if ((d2 < best) || ((d2 == best) && (jg < bjg))){
            best = d2; bjg = jg; brg = gg.x; bcg = gg.y;
          }
        }
      }
    }
    for (int off = 8; off; off >>= 1){
      float ob = __shfl_xor(best, off, 64);
      int   oj = __shfl_xor(bjg,  off, 64);
      float orr = __shfl_xor(brg, off, 64);
      float oc = __shfl_xor(bcg, off, 64);
      if ((ob < best) || ((ob == best) && (oj < bjg))){
        best = ob; bjg = oj; brg = orr; bcg = oc;
      }
    }
  }
  // epilogue: all lanes of group redundantly; lane 0 of group stores
  float ar = rp - (float)r0, ac = cp - (float)c0;
  float omr = 1.0f - ar, omc = 1.0f - ac;
  float wa = omr*omc, wb = omr*ac, wc = ar*omc, wd = ar*ac;
  float nr = (((na.x*wa) + (nb.x*wb)) + (ncn.x*wc)) + (nd.x*wd);
  float nc = (((na.y*wa) + (nb.y*wb)) + (ncn.y*wc)) + (nd.y*wd);
  float nrm = sqrtf((nr*nr) + (nc*nc));
  float den = nrm + 1e-8f;
  float nru = nr / den, ncu = nc / den;
  float dr = brg - rp, dc = bcg - cp;  // winner coords carried in-register
  float dotv = (dr*nru) + (dc*ncu);
  int contrib = m && (best <= 9.0f);
  float vals = (((pa*wa) + (pb*wb)) + (pc*wc)) + (pd*wd);
  __shared__ double sb[16];
  if (l == 0){
    dotA[k] = contrib ? dotv : 0.0f;
    sb[g] = m ? (double)vals : 0.0;
  }
  __syncthreads();
  if (tid == 0){
    double acc = 0.0;
    for (int q = 0; q < 16; ++q) acc += sb[q];
    pvPart[blockIdx.x] = acc;
  }
}

// ---- K3: ordered scatter replication + fused last-block final reduction ---
__global__ __launch_bounds__(128) void k_pixfinal(
    const float* __restrict__ PR, const float2* __restrict__ prP,
    const float* __restrict__ dotA, const double* __restrict__ pvPart,
    float* tmp, int* finCnt, float* out){
#pragma clang fp contract(off)
  int p = blockIdx.x*128 + threadIdx.x;   // exactly NPIX threads
  int i = p / WW, j = p % WW;
  float s = 0.0f;
  // pass1 vertical: wa = (1-ar) at (r0, j)
  for (int i0 = i-1; i0 <= i; ++i0){
    if (i0 < 0 || i0 > HH-2) continue;
    int k = i0*WW + j;
    float r = prP[k].x;
    int r0 = (int)floorf(r);
    if (r0 == i){
      float ar = r - (float)r0;
      float w = 1.0f - ar;
      s = s + (dotA[k] * w);
    }
  }
  // pass1 horizontal: wa = (1-ac) at (i, c0)
  for (int j0 = j-1; j0 <= j; ++j0){
    if (j0 < 0 || j0 > WW-2) continue;
    int k = NV + i*(WW-1) + j0;
    float c = prP[k].y;
    int c0 = (int)floorf(c);
    if (c0 == j){
      float ac = c - (float)c0;
      float w = 1.0f - ac;
      s = s + (dotA[k] * w);
    }
  }
  // pass2 horizontal: wb = ac at (i, c0+1)
  for (int j0 = j-2; j0 <= j-1; ++j0){
    if (j0 < 0 || j0 > WW-2) continue;
    int k = NV + i*(WW-1) + j0;
    float c = prP[k].y;
    int c0 = (int)floorf(c);
    if (c0 == j-1){
      float ac = c - (float)c0;
      s = s + (dotA[k] * ac);
    }
  }
  // pass3 vertical: wc = ar at (r0+1, j)
  for (int i0 = i-2; i0 <= i-1; ++i0){
    if (i0 < 0 || i0 > HH-2) continue;
    int k = i0*WW + j;
    float r = prP[k].x;
    int r0 = (int)floorf(r);
    if (r0 == i-1){
      float ar = r - (float)r0;
      s = s + (dotA[k] * ar);
    }
  }
  tmp[p] = PR[p] * s;
  // release our tmp writes, count this block done
  __threadfence();
  __syncthreads();
  __shared__ int lastFlag;
  if (threadIdx.x == 0){
    int old = atomicAdd(finCnt, 1);      // device-scope
    lastFlag = (old == PBLK-1);
  }
  __syncthreads();
  if (!lastFlag) return;
  __threadfence();                       // acquire: see all blocks' tmp
  // numpy pairwise sum (128 leaves x 72, identical order) + pix double sum
  __shared__ float buf[128];
  __shared__ double dbuf[128];
  int t = threadIdx.x;
  const float4* a4 = (const float4*)(tmp + t*72);
  float4 x = a4[0], y = a4[1];
  float q0=x.x, q1=x.y, q2=x.z, q3=x.w, q4=y.x, q5=y.y, q6=y.z, q7=y.w;
  for (int i4 = 2; i4 < 18; i4 += 2){
    float4 u = a4[i4], v = a4[i4+1];
    q0 += u.x; q1 += u.y; q2 += u.z; q3 += u.w;
    q4 += v.x; q5 += v.y; q6 += v.z; q7 += v.w;
  }
  buf[t] = ((q0+q1)+(q2+q3)) + ((q4+q5)+(q6+q7));
  double pv = 0.0;
  for (int idx = t; idx < NBLK2; idx += 128) pv += pvPart[idx];
  dbuf[t] = pv;
  __syncthreads();
  for (int st = 1; st < 128; st <<= 1){
    if ((t & (2*st - 1)) == 0){
      buf[t]  = buf[t]  + buf[t+st];
      dbuf[t] = dbuf[t] + dbuf[t+st];
    }
    __syncthreads();
  }
  if (t == 0) out[0] = buf[0] + (float)dbuf[0];
}

extern "C" void kernel_launch(void* const* d_in, const int* in_sizes, int n_in,
                              void* d_out, int out_size, void* d_ws, size_t ws_size,
                              hipStream_t stream){
  const float* pred = (const float*)d_in[0];
  const float* gt   = (const float*)d_in[1];
  float* out = (float*)d_out;

  char* w = (char*)d_ws;
  float4* cells  = (float4*)w;                 w += (size_t)NCELL*SLOTS*sizeof(float4); // 589824
  double* pvPart = (double*)w;                 w += (size_t)NBLK2*sizeof(double);
  float2* N2     = (float2*)w;                 w += (size_t)NPIX*sizeof(float2);
  float2* prP    = (float2*)w;                 w += (size_t)NC*sizeof(float2);
  float*  dotA   = (float*)w;                  w += (size_t)NC*sizeof(float);
  float*  tmp    = (float*)w;                  w += (size_t)NPIX*sizeof(float);
  int*    prM    = (int*)w;                    w += (size_t)NC*sizeof(int);
  int*    finCnt = (int*)w;

  k_prep<<<dim3(108), dim3(256), 0, stream>>>(pred, gt, N2, prP, prM,
                                              cells, finCnt);
  k_nndot<<<dim3(NBLK2), dim3(256), 0, stream>>>(pred, N2, prP, prM,
                                                 cells, dotA, pvPart);
  k_pixfinal<<<dim3(PBLK), dim3(128), 0, stream>>>(pred, prP, dotA,
                                                   pvPart, tmp, finCnt, out);
}